// Round 8
// baseline (217.458 us; speedup 1.0000x reference)
//
#include <hip/hip_runtime.h>
#include <cstdint>
#include <cstddef>

#define NN  768
#define IND 64
#define HD  128
#define EFD 16
#define TT  3
#define NC  16      // i-chunks in msgmax
#define CHUNK 48    // 768/NC

typedef __attribute__((ext_vector_type(8)))  short short8;
typedef __attribute__((ext_vector_type(16))) float floatx16;

__device__ __forceinline__ unsigned f2bf(float f){
    unsigned u = __float_as_uint(f);
    return (u + 0x7FFFu + ((u >> 16) & 1u)) >> 16;
}

// ---------- K1: z(0)+zsrc/zdst(0) row-local; edges f32->bf16; weight transposes; output init ----------
__global__ __launch_bounds__(256)
void k1_ker(const float* __restrict__ states, const float* __restrict__ edges,
            const float* __restrict__ We, const float* __restrict__ be,
            const float* __restrict__ Wm, const float* __restrict__ Wu,
            const float* __restrict__ Wd, float* __restrict__ out,
            float* __restrict__ z, float* __restrict__ zsrc, float* __restrict__ zdst,
            unsigned short* __restrict__ ebf, float* __restrict__ tw)
{
    int bid = blockIdx.x, tid = threadIdx.x;
    __shared__ float sZ[HD];
    if (tid < HD){
        float acc = be[tid];
        const float* srow = states + bid * IND;
        #pragma unroll
        for (int k = 0; k < IND; ++k) acc += srow[k] * We[k * HD + tid];
        z[bid * HD + tid] = acc;
        sZ[tid] = acc;
    }
    __syncthreads();
    {
        int h = tid & 127, which = tid >> 7;
        const float* W = Wm + which * HD * HD;
        float acc = 0.f;
        #pragma unroll 8
        for (int k = 0; k < HD; ++k) acc += sZ[k] * W[k * HD + h];
        (which ? zdst : zsrc)[bid * HD + h] = acc;
    }
    // edges conv: 2359296 float4 over 768*256 threads = 12 iters
    const float4* ef4 = reinterpret_cast<const float4*>(edges);
    uint2* eb2 = reinterpret_cast<uint2*>(ebf);
    int gid0 = bid * 256 + tid;
    for (int it = 0; it < 12; ++it){
        int gid = gid0 + it * 196608;
        float4 v = ef4[gid];
        uint2 p;
        p.x = f2bf(v.x) | (f2bf(v.y) << 16);
        p.y = f2bf(v.z) | (f2bf(v.w) << 16);
        eb2[gid] = p;
    }
    // weight transposes: 106496 elements, blocks 0..103, 4 elems/thread
    // layout in tw: WuT[128][256] @0 | WdT[64][256] @32768 | WeT[128][192] @49152
    //              WmST[128][128] @73728 | WmDT[128][128] @90112
    if (bid < 104){
        #pragma unroll
        for (int e = 0; e < 4; ++e){
            int eidx = bid * 1024 + tid * 4 + e;
            float v;
            if (eidx < 32768){ int h = eidx >> 8, k = eidx & 255; v = Wu[k * HD + h]; }
            else if (eidx < 49152){ int r = eidx - 32768; int c = r >> 8, k = r & 255; v = Wd[k * IND + c]; }
            else if (eidx < 73728){ int r = eidx - 49152; int h = r / 192, k = r - h * 192; v = We[k * HD + h]; }
            else if (eidx < 90112){ int r = eidx - 73728; int h = r >> 7, k = r & 127; v = Wm[k * HD + h]; }
            else { int r = eidx - 90112; int h = r >> 7, k = r & 127; v = Wm[(HD + k) * HD + h]; }
            tw[eidx] = v;
        }
    }
    if (gid0 < NN * IND){ int n = gid0 >> 6, c = gid0 & 63; out[n * 256 + c] = states[n * IND + c]; }
    if (gid0 < NN * 2){ int n = gid0 >> 1, cc = gid0 & 1; out[196608 + n * 8 + cc] = 0.f; }
}

// ---------- K2: MFMA msgmax (blocks 0..383) ; msbuf zero + deferred stop(t-1) (blocks 384..511) ----------
__global__ __launch_bounds__(256)
void k2_ker(const unsigned short* __restrict__ ebf, const float* __restrict__ zsrc,
            const float* __restrict__ Wm, float* __restrict__ partial,
            const float* __restrict__ hid, unsigned long long* __restrict__ msbuf,
            const float* __restrict__ Wt, const float* __restrict__ bt,
            float* __restrict__ out, int t)
{
    int bid = blockIdx.x, tid = threadIdx.x;
    if (bid < 384){
        const float* WmE = Wm + 2 * HD * HD;
        int lane = tid & 63;
        int wv = tid >> 6;
        int jt = bid % 24, ch = bid / 24;
        int j0 = jt * 32, h0 = wv * 32, i0 = ch * CHUNK;
        int ln = lane & 31, lh = lane >> 5;

        short8 b;
        #pragma unroll
        for (int q = 0; q < 8; ++q)
            b[q] = (short)f2bf(WmE[(8 * lh + q) * HD + h0 + ln]);

        floatx16 czero, run;
        #pragma unroll
        for (int r = 0; r < 16; ++r){ czero[r] = 0.f; run[r] = -INFINITY; }

        const unsigned short* abase = ebf + (size_t)(j0 + ln) * EFD + 8 * lh;
        #pragma unroll 2
        for (int ii = 0; ii < CHUNK; ++ii){
            int i = i0 + ii;
            short8 a = *reinterpret_cast<const short8*>(abase + (size_t)i * NN * EFD);
            float zsv = zsrc[i * HD + h0 + ln];
            floatx16 d = __builtin_amdgcn_mfma_f32_32x32x16_bf16(a, b, czero, 0, 0, 0);
            #pragma unroll
            for (int r = 0; r < 16; ++r) run[r] = fmaxf(run[r], d[r] + zsv);
        }
        float* pb = partial + ((size_t)ch * NN + j0) * HD + h0 + ln;
        #pragma unroll
        for (int r = 0; r < 16; ++r){
            int row = (r & 3) + 8 * (r >> 2) + 4 * lh;
            pb[(size_t)row * HD] = run[r];
        }
    } else {
        int b2 = bid - 384;
        if (b2 == 0 && tid < HD) msbuf[(t & 1) * HD + tid] = 0ull;
        if (t > 0 && tid < 12){
            int row = b2 * 6 + (tid >> 1), cc = tid & 1;
            float a2 = bt[cc];
            const float* hrow = hid + row * HD;
            #pragma unroll 8
            for (int k = 0; k < HD; ++k) a2 += hrow[k] * Wt[k * 2 + cc];
            const unsigned long long* msp = msbuf + ((t - 1) & 1) * HD;
            const float sc = 1.0f / (768.0f * 1048576.0f);
            #pragma unroll 8
            for (int k = 0; k < HD; ++k){
                float mk = (float)(long long)msp[k] * sc;
                a2 += mk * Wt[(HD + k) * 2 + cc];
            }
            out[196608 + row * 8 + t * 2 + cc] = 1.f / (1.f + expf(-a2));
        }
    }
}

// ---------- K3: hnew + meansum + new_state/preds + z(t+1) + zsrc/zdst(t+1), 2 rows/block ----------
__global__ __launch_bounds__(256)
void k3_ker(float* __restrict__ z, float* __restrict__ zsrc, float* __restrict__ zdst,
            const float* __restrict__ partial, const float* __restrict__ bm,
            const float* __restrict__ bu, const float* __restrict__ bd,
            const float* __restrict__ be, const float* __restrict__ tw,
            float* __restrict__ hid, float* __restrict__ state,
            unsigned long long* __restrict__ msbuf, float* __restrict__ out, int t)
{
    const float* WuT  = tw;            // [128][256]
    const float* WdT  = tw + 32768;    // [64][256]
    const float* WeT  = tw + 49152;    // [128][192]
    const float* WmST = tw + 73728;    // [128][128]
    const float* WmDT = tw + 90112;    // [128][128]

    __shared__ float sA[2][256];   // [mm][k]: k<128 z, k>=128 u
    __shared__ float sH[2][HD];
    __shared__ float sS[2][IND];
    __shared__ float sZp[2][HD];
    int tid = threadIdx.x;
    int m0 = blockIdx.x * 2;

    #pragma unroll
    for (int r = 0; r < 2; ++r){
        int idx = tid + r * 256;
        int mm = idx >> 8, k = idx & 255;
        float v;
        if (k < HD) v = z[(m0 + mm) * HD + k];
        else {
            int kk = k - HD;
            float mx = -INFINITY;
            #pragma unroll
            for (int c2 = 0; c2 < NC; ++c2)
                mx = fmaxf(mx, partial[((size_t)c2 * NN + (m0 + mm)) * HD + kk]);
            v = mx + zdst[(m0 + mm) * HD + kk] + bm[kk];
        }
        sA[mm][k] = v;
    }
    __syncthreads();

    int mm = tid >> 7, h = tid & 127;
    {
        const float4* wr = reinterpret_cast<const float4*>(WuT + (size_t)h * 256);
        float4 a4 = make_float4(0.f, 0.f, 0.f, 0.f);
        #pragma unroll
        for (int q = 0; q < 64; ++q){
            float4 w = wr[q];
            float4 s = *reinterpret_cast<const float4*>(&sA[mm][4 * q]);
            a4.x += s.x * w.x; a4.y += s.y * w.y; a4.z += s.z * w.z; a4.w += s.w * w.w;
        }
        float acc = bu[h] + ((a4.x + a4.y) + (a4.z + a4.w));
        hid[(m0 + mm) * HD + h] = acc;
        sH[mm][h] = acc;
    }
    __syncthreads();

    if (tid < HD){
        long long s = llrintf(sH[0][tid] * 1048576.f) + llrintf(sH[1][tid] * 1048576.f);
        atomicAdd(&msbuf[(t & 1) * HD + tid], (unsigned long long)s);
    }
    if (tid < 128){
        int c = tid & 63, mm2 = tid >> 6;
        const float4* wr = reinterpret_cast<const float4*>(WdT + (size_t)c * 256);
        float4 a4 = make_float4(0.f, 0.f, 0.f, 0.f);
        #pragma unroll
        for (int q = 0; q < 32; ++q){            // k 0..127 -> h_new (sH)
            float4 w = wr[q];
            float4 s = *reinterpret_cast<const float4*>(&sH[mm2][4 * q]);
            a4.x += s.x * w.x; a4.y += s.y * w.y; a4.z += s.z * w.z; a4.w += s.w * w.w;
        }
        #pragma unroll
        for (int q = 32; q < 64; ++q){           // k 128..255 -> z (sA[..][0..127])
            float4 w = wr[q];
            float4 s = *reinterpret_cast<const float4*>(&sA[mm2][4 * q - 128]);
            a4.x += s.x * w.x; a4.y += s.y * w.y; a4.z += s.z * w.z; a4.w += s.w * w.w;
        }
        float a = bd[c] + ((a4.x + a4.y) + (a4.z + a4.w));
        state[(m0 + mm2) * IND + c] = a;
        out[(m0 + mm2) * 256 + (t + 1) * IND + c] = a;
        sS[mm2][c] = a;
    }
    __syncthreads();

    if (t < TT - 1){
        const float4* wr = reinterpret_cast<const float4*>(WeT + (size_t)h * 192);
        float4 a4 = make_float4(0.f, 0.f, 0.f, 0.f);
        #pragma unroll
        for (int q = 0; q < 16; ++q){            // k 0..63 -> state' (sS)
            float4 w = wr[q];
            float4 s = *reinterpret_cast<const float4*>(&sS[mm][4 * q]);
            a4.x += s.x * w.x; a4.y += s.y * w.y; a4.z += s.z * w.z; a4.w += s.w * w.w;
        }
        #pragma unroll
        for (int q = 16; q < 48; ++q){           // k 64..191 -> h_new (sH)
            float4 w = wr[q];
            float4 s = *reinterpret_cast<const float4*>(&sH[mm][4 * q - 64]);
            a4.x += s.x * w.x; a4.y += s.y * w.y; a4.z += s.z * w.z; a4.w += s.w * w.w;
        }
        float acc2 = be[h] + ((a4.x + a4.y) + (a4.z + a4.w));
        z[(m0 + mm) * HD + h] = acc2;
        sZp[mm][h] = acc2;
        __syncthreads();

        const float4* ws4 = reinterpret_cast<const float4*>(WmST + (size_t)h * 128);
        const float4* wd4 = reinterpret_cast<const float4*>(WmDT + (size_t)h * 128);
        float4 aS = make_float4(0.f, 0.f, 0.f, 0.f);
        float4 aD = make_float4(0.f, 0.f, 0.f, 0.f);
        #pragma unroll
        for (int q = 0; q < 32; ++q){
            float4 s = *reinterpret_cast<const float4*>(&sZp[mm][4 * q]);
            float4 w1 = ws4[q];
            float4 w2 = wd4[q];
            aS.x += s.x * w1.x; aS.y += s.y * w1.y; aS.z += s.z * w1.z; aS.w += s.w * w1.w;
            aD.x += s.x * w2.x; aD.y += s.y * w2.y; aD.z += s.z * w2.z; aD.w += s.w * w2.w;
        }
        zsrc[(m0 + mm) * HD + h] = (aS.x + aS.y) + (aS.z + aS.w);
        zdst[(m0 + mm) * HD + h] = (aD.x + aD.y) + (aD.z + aD.w);
    }
}

// ---------- final stop (t = TT-1) ----------
__global__ void kstop_ker(const float* __restrict__ hid, const unsigned long long* __restrict__ msbuf,
                          const float* __restrict__ Wt, const float* __restrict__ bt,
                          float* __restrict__ out)
{
    int tid = threadIdx.x;
    if (tid < 12){
        int row = blockIdx.x * 6 + (tid >> 1), cc = tid & 1;
        float a2 = bt[cc];
        const float* hrow = hid + row * HD;
        #pragma unroll 8
        for (int k = 0; k < HD; ++k) a2 += hrow[k] * Wt[k * 2 + cc];
        const unsigned long long* msp = msbuf + ((TT - 1) & 1) * HD;
        const float sc = 1.0f / (768.0f * 1048576.0f);
        #pragma unroll 8
        for (int k = 0; k < HD; ++k){
            float mk = (float)(long long)msp[k] * sc;
            a2 += mk * Wt[(HD + k) * 2 + cc];
        }
        out[196608 + row * 8 + TT * 2 + cc] = 1.f / (1.f + expf(-a2));
    }
}

extern "C" void kernel_launch(void* const* d_in, const int* in_sizes, int n_in,
                              void* d_out, int out_size, void* d_ws, size_t ws_size,
                              hipStream_t stream){
    const float* states = (const float*)d_in[0];
    const float* edges  = (const float*)d_in[1];
    const float* We = (const float*)d_in[2];
    const float* be = (const float*)d_in[3];
    const float* Wm = (const float*)d_in[4];
    const float* bm = (const float*)d_in[5];
    const float* Wu = (const float*)d_in[6];
    const float* bu = (const float*)d_in[7];
    const float* Wd = (const float*)d_in[8];
    const float* bd = (const float*)d_in[9];
    const float* Wt = (const float*)d_in[10];
    const float* bt = (const float*)d_in[11];
    float* out = (float*)d_out;

    float* ws = (float*)d_ws;
    float* z       = ws;                        // 98304
    float* zsrc    = ws + 98304;                // 98304
    float* zdst    = ws + 196608;               // 98304
    float* hid     = ws + 294912;               // 98304
    float* state   = ws + 393216;               // 49152
    unsigned long long* msbuf = (unsigned long long*)(ws + 442368); // 256 ull
    float* partial = ws + 443136;               // 16*768*128 = 1572864
    unsigned short* ebf = (unsigned short*)(ws + 2016000); // 9437184 bf16 = 4718592 floats
    float* tw      = ws + 6734592;              // 106496 transposed weights

    k1_ker<<<768, 256, 0, stream>>>(states, edges, We, be, Wm, Wu, Wd, out, z, zsrc, zdst, ebf, tw);
    for (int t = 0; t < TT; ++t){
        k2_ker<<<512, 256, 0, stream>>>(ebf, zsrc, Wm, partial, hid, msbuf, Wt, bt, out, t);
        k3_ker<<<384, 256, 0, stream>>>(z, zsrc, zdst, partial, bm, bu, bd, be, tw,
                                        hid, state, msbuf, out, t);
    }
    kstop_ker<<<128, 256, 0, stream>>>(hid, msbuf, Wt, bt, out);
}

// Round 9
// 163.952 us; speedup vs baseline: 1.3264x; 1.3264x over previous
//
#include <hip/hip_runtime.h>
#include <cstdint>
#include <cstddef>

#define NN  768
#define IND 64
#define HD  128
#define EFD 16
#define TT  3
#define NC  16      // i-chunks in msgmax
#define CHUNK 48    // 768/NC

typedef __attribute__((ext_vector_type(8)))  short short8;
typedef __attribute__((ext_vector_type(16))) float floatx16;

__device__ __forceinline__ unsigned f2bf(float f){
    unsigned u = __float_as_uint(f);
    return (u + 0x7FFFu + ((u >> 16) & 1u)) >> 16;
}
// monotonic uint encoding of float for atomicMax
__device__ __forceinline__ unsigned enc_f(float f){
    unsigned b = __float_as_uint(f);
    return (b & 0x80000000u) ? ~b : (b | 0x80000000u);
}
__device__ __forceinline__ float dec_f(unsigned e){
    return __uint_as_float((e & 0x80000000u) ? (e & 0x7FFFFFFFu) : ~e);
}
#define ENC_NEG_INF 0x007FFFFFu

// ---------- K1: z(0)+zsrc/zdst(0) row-local; edges f32->bf16; u_enc init; output init ----------
__global__ __launch_bounds__(256)
void k1_ker(const float* __restrict__ states, const float* __restrict__ edges,
            const float* __restrict__ We, const float* __restrict__ be,
            const float* __restrict__ Wm, float* __restrict__ out,
            float* __restrict__ z, float* __restrict__ zsrc, float* __restrict__ zdst,
            unsigned short* __restrict__ ebf, unsigned* __restrict__ u_enc)
{
    int bid = blockIdx.x, tid = threadIdx.x;
    __shared__ float sZ[HD];
    if (tid < HD){
        float acc = be[tid];
        const float* srow = states + bid * IND;
        #pragma unroll
        for (int k = 0; k < IND; ++k) acc += srow[k] * We[k * HD + tid];
        z[bid * HD + tid] = acc;
        sZ[tid] = acc;
    }
    __syncthreads();
    {
        int h = tid & 127, which = tid >> 7;
        const float* W = Wm + which * HD * HD;
        float acc = 0.f;
        #pragma unroll 8
        for (int k = 0; k < HD; ++k) acc += sZ[k] * W[k * HD + h];
        (which ? zdst : zsrc)[bid * HD + h] = acc;
    }
    // edges conv: 2359296 float4 over 768*256 threads = 12 iters
    const float4* ef4 = reinterpret_cast<const float4*>(edges);
    uint2* eb2 = reinterpret_cast<uint2*>(ebf);
    int gid0 = bid * 256 + tid;
    for (int it = 0; it < 12; ++it){
        int gid = gid0 + it * 196608;
        float4 v = ef4[gid];
        uint2 p;
        p.x = f2bf(v.x) | (f2bf(v.y) << 16);
        p.y = f2bf(v.z) | (f2bf(v.w) << 16);
        eb2[gid] = p;
    }
    // u_enc init: 3*768*128 = 294912 over 196608 threads
    u_enc[gid0] = ENC_NEG_INF;
    if (gid0 < 98304) u_enc[196608 + gid0] = ENC_NEG_INF;
    if (gid0 < NN * IND){ int n = gid0 >> 6, c = gid0 & 63; out[n * 256 + c] = states[n * IND + c]; }
    if (gid0 < NN * 2){ int n = gid0 >> 1, cc = gid0 & 1; out[196608 + n * 8 + cc] = 0.f; }
}

// ---------- K2: MFMA msgmax -> atomicMax u_enc[t] (blocks 0..383); msbuf zero + stop(t-1) (384..511) ----------
__global__ __launch_bounds__(256)
void k2_ker(const unsigned short* __restrict__ ebf, const float* __restrict__ zsrc,
            const float* __restrict__ Wm, unsigned* __restrict__ u_enc,
            const float* __restrict__ hid, unsigned long long* __restrict__ msbuf,
            const float* __restrict__ Wt, const float* __restrict__ bt,
            float* __restrict__ out, int t)
{
    int bid = blockIdx.x, tid = threadIdx.x;
    if (bid < 384){
        const float* WmE = Wm + 2 * HD * HD;
        int lane = tid & 63;
        int wv = tid >> 6;
        int jt = bid % 24, ch = bid / 24;
        int j0 = jt * 32, h0 = wv * 32, i0 = ch * CHUNK;
        int ln = lane & 31, lh = lane >> 5;

        short8 b;
        #pragma unroll
        for (int q = 0; q < 8; ++q)
            b[q] = (short)f2bf(WmE[(8 * lh + q) * HD + h0 + ln]);

        floatx16 czero, run;
        #pragma unroll
        for (int r = 0; r < 16; ++r){ czero[r] = 0.f; run[r] = -INFINITY; }

        const unsigned short* abase = ebf + (size_t)(j0 + ln) * EFD + 8 * lh;
        #pragma unroll 2
        for (int ii = 0; ii < CHUNK; ++ii){
            int i = i0 + ii;
            short8 a = *reinterpret_cast<const short8*>(abase + (size_t)i * NN * EFD);
            float zsv = zsrc[i * HD + h0 + ln];
            floatx16 d = __builtin_amdgcn_mfma_f32_32x32x16_bf16(a, b, czero, 0, 0, 0);
            #pragma unroll
            for (int r = 0; r < 16; ++r) run[r] = fmaxf(run[r], d[r] + zsv);
        }
        unsigned* ub = u_enc + t * (NN * HD) + j0 * HD + h0 + ln;
        #pragma unroll
        for (int r = 0; r < 16; ++r){
            int row = (r & 3) + 8 * (r >> 2) + 4 * lh;
            atomicMax(ub + row * HD, enc_f(run[r]));
        }
    } else {
        int b2 = bid - 384;
        if (b2 == 0 && tid < HD) msbuf[(t & 1) * HD + tid] = 0ull;
        if (t > 0 && tid < 12){
            int row = b2 * 6 + (tid >> 1), cc = tid & 1;
            float a2 = bt[cc];
            const float* hrow = hid + row * HD;
            #pragma unroll 8
            for (int k = 0; k < HD; ++k) a2 += hrow[k] * Wt[k * 2 + cc];
            const unsigned long long* msp = msbuf + ((t - 1) & 1) * HD;
            const float sc = 1.0f / (768.0f * 1048576.0f);
            #pragma unroll 8
            for (int k = 0; k < HD; ++k){
                float mk = (float)(long long)msp[k] * sc;
                a2 += mk * Wt[(HD + k) * 2 + cc];
            }
            out[196608 + row * 8 + t * 2 + cc] = 1.f / (1.f + expf(-a2));
        }
    }
}

// ---------- K3: hnew + meansum + new_state/preds + z(t+1) + zsrc/zdst(t+1), 2 rows/block ----------
__global__ __launch_bounds__(256)
void k3_ker(float* __restrict__ z, float* __restrict__ zsrc, float* __restrict__ zdst,
            const unsigned* __restrict__ u_enc, const float* __restrict__ bm,
            const float* __restrict__ Wu, const float* __restrict__ bu,
            const float* __restrict__ Wd, const float* __restrict__ bd,
            const float* __restrict__ We, const float* __restrict__ be,
            const float* __restrict__ Wm,
            float* __restrict__ hid, float* __restrict__ state,
            unsigned long long* __restrict__ msbuf, float* __restrict__ out, int t)
{
    __shared__ float sA[2][256];   // [mm][k]: k<128 z, k>=128 u
    __shared__ float sH[2][HD];
    __shared__ float sS[2][IND];
    __shared__ float sZp[2][HD];
    int tid = threadIdx.x;
    int m0 = blockIdx.x * 2;

    #pragma unroll
    for (int r = 0; r < 2; ++r){
        int idx = tid + r * 256;
        int mm = idx >> 8, k = idx & 255;
        float v;
        if (k < HD) v = z[(m0 + mm) * HD + k];
        else {
            int kk = k - HD;
            float mx = dec_f(u_enc[t * (NN * HD) + (m0 + mm) * HD + kk]);
            v = mx + zdst[(m0 + mm) * HD + kk] + bm[kk];
        }
        sA[mm][k] = v;
    }
    __syncthreads();

    int mm = tid >> 7, h = tid & 127;
    {
        float acc = bu[h];
        #pragma unroll 8
        for (int k = 0; k < 256; ++k) acc += sA[mm][k] * Wu[k * HD + h];
        hid[(m0 + mm) * HD + h] = acc;
        sH[mm][h] = acc;
    }
    __syncthreads();

    if (tid < HD){
        long long s = llrintf(sH[0][tid] * 1048576.f) + llrintf(sH[1][tid] * 1048576.f);
        atomicAdd(&msbuf[(t & 1) * HD + tid], (unsigned long long)s);
    }
    if (tid < 128){
        int c = tid & 63, mm2 = tid >> 6;
        float a = bd[c];
        #pragma unroll 8
        for (int k = 0; k < HD; ++k) a += sH[mm2][k] * Wd[k * IND + c];
        #pragma unroll 8
        for (int k = 0; k < HD; ++k) a += sA[mm2][k] * Wd[(HD + k) * IND + c];
        state[(m0 + mm2) * IND + c] = a;
        out[(m0 + mm2) * 256 + (t + 1) * IND + c] = a;
        sS[mm2][c] = a;
    }
    __syncthreads();

    if (t < TT - 1){
        float acc2 = be[h];
        #pragma unroll
        for (int k = 0; k < IND; ++k) acc2 += sS[mm][k] * We[k * HD + h];
        #pragma unroll 8
        for (int k = 0; k < HD; ++k) acc2 += sH[mm][k] * We[(IND + k) * HD + h];
        z[(m0 + mm) * HD + h] = acc2;
        sZp[mm][h] = acc2;
        __syncthreads();

        float accS = 0.f, accD = 0.f;
        #pragma unroll 8
        for (int k = 0; k < HD; ++k){
            float v = sZp[mm][k];
            accS += v * Wm[k * HD + h];
            accD += v * Wm[(HD + k) * HD + h];
        }
        zsrc[(m0 + mm) * HD + h] = accS;
        zdst[(m0 + mm) * HD + h] = accD;
    }
}

// ---------- final stop (t = TT-1) ----------
__global__ void kstop_ker(const float* __restrict__ hid, const unsigned long long* __restrict__ msbuf,
                          const float* __restrict__ Wt, const float* __restrict__ bt,
                          float* __restrict__ out)
{
    int tid = threadIdx.x;
    if (tid < 12){
        int row = blockIdx.x * 6 + (tid >> 1), cc = tid & 1;
        float a2 = bt[cc];
        const float* hrow = hid + row * HD;
        #pragma unroll 8
        for (int k = 0; k < HD; ++k) a2 += hrow[k] * Wt[k * 2 + cc];
        const unsigned long long* msp = msbuf + ((TT - 1) & 1) * HD;
        const float sc = 1.0f / (768.0f * 1048576.0f);
        #pragma unroll 8
        for (int k = 0; k < HD; ++k){
            float mk = (float)(long long)msp[k] * sc;
            a2 += mk * Wt[(HD + k) * 2 + cc];
        }
        out[196608 + row * 8 + TT * 2 + cc] = 1.f / (1.f + expf(-a2));
    }
}

extern "C" void kernel_launch(void* const* d_in, const int* in_sizes, int n_in,
                              void* d_out, int out_size, void* d_ws, size_t ws_size,
                              hipStream_t stream){
    const float* states = (const float*)d_in[0];
    const float* edges  = (const float*)d_in[1];
    const float* We = (const float*)d_in[2];
    const float* be = (const float*)d_in[3];
    const float* Wm = (const float*)d_in[4];
    const float* bm = (const float*)d_in[5];
    const float* Wu = (const float*)d_in[6];
    const float* bu = (const float*)d_in[7];
    const float* Wd = (const float*)d_in[8];
    const float* bd = (const float*)d_in[9];
    const float* Wt = (const float*)d_in[10];
    const float* bt = (const float*)d_in[11];
    float* out = (float*)d_out;

    float* ws = (float*)d_ws;
    float* z       = ws;                        // 98304
    float* zsrc    = ws + 98304;                // 98304
    float* zdst    = ws + 196608;               // 98304
    float* hid     = ws + 294912;               // 98304
    float* state   = ws + 393216;               // 49152
    unsigned long long* msbuf = (unsigned long long*)(ws + 442368); // 256 ull = 512 f
    unsigned* u_enc = (unsigned*)(ws + 442880); // 3*768*128 = 294912 u32
    unsigned short* ebf = (unsigned short*)(ws + 737792); // 9437184 bf16

    k1_ker<<<768, 256, 0, stream>>>(states, edges, We, be, Wm, out, z, zsrc, zdst, ebf, u_enc);
    for (int t = 0; t < TT; ++t){
        k2_ker<<<512, 256, 0, stream>>>(ebf, zsrc, Wm, u_enc, hid, msbuf, Wt, bt, out, t);
        k3_ker<<<384, 256, 0, stream>>>(z, zsrc, zdst, u_enc, bm, Wu, bu, Wd, bd,
                                        We, be, Wm, hid, state, msbuf, out, t);
    }
    kstop_ker<<<128, 256, 0, stream>>>(hid, msbuf, Wt, bt, out);
}

// Round 10
// 157.950 us; speedup vs baseline: 1.3768x; 1.0380x over previous
//
#include <hip/hip_runtime.h>
#include <cstdint>
#include <cstddef>

#define NN  768
#define IND 64
#define HD  128
#define EFD 16
#define TT  3
#define NC  16      // i-chunks in msgmax
#define CHUNK 48    // 768/NC

typedef __attribute__((ext_vector_type(8)))  short short8;
typedef __attribute__((ext_vector_type(16))) float floatx16;

__device__ __forceinline__ unsigned f2bf(float f){
    unsigned u = __float_as_uint(f);
    return (u + 0x7FFFu + ((u >> 16) & 1u)) >> 16;
}
// monotonic uint encoding of float for atomicMax
__device__ __forceinline__ unsigned enc_f(float f){
    unsigned b = __float_as_uint(f);
    return (b & 0x80000000u) ? ~b : (b | 0x80000000u);
}
__device__ __forceinline__ float dec_f(unsigned e){
    return __uint_as_float((e & 0x80000000u) ? (e & 0x7FFFFFFFu) : ~e);
}
#define ENC_NEG_INF 0x007FFFFFu

// ---------- K1: z(0)+zsrc/zdst(0) row-local; edges f32->bf16; u_enc init; output init ----------
__global__ __launch_bounds__(256)
void k1_ker(const float* __restrict__ states, const float* __restrict__ edges,
            const float* __restrict__ We, const float* __restrict__ be,
            const float* __restrict__ Wm, float* __restrict__ out,
            float* __restrict__ z, float* __restrict__ zsrc, float* __restrict__ zdst,
            unsigned short* __restrict__ ebf, unsigned* __restrict__ u_enc)
{
    int bid = blockIdx.x, tid = threadIdx.x;
    __shared__ float sZ[HD];
    if (tid < HD){
        float acc = be[tid];
        const float* srow = states + bid * IND;
        #pragma unroll
        for (int k = 0; k < IND; ++k) acc += srow[k] * We[k * HD + tid];
        z[bid * HD + tid] = acc;
        sZ[tid] = acc;
    }
    __syncthreads();
    {
        int h = tid & 127, which = tid >> 7;
        const float* W = Wm + which * HD * HD;
        float acc = 0.f;
        #pragma unroll 8
        for (int k = 0; k < HD; ++k) acc += sZ[k] * W[k * HD + h];
        (which ? zdst : zsrc)[bid * HD + h] = acc;
    }
    // edges conv: 2359296 float4 over 768*256 threads = 12 iters
    const float4* ef4 = reinterpret_cast<const float4*>(edges);
    uint2* eb2 = reinterpret_cast<uint2*>(ebf);
    int gid0 = bid * 256 + tid;
    for (int it = 0; it < 12; ++it){
        int gid = gid0 + it * 196608;
        float4 v = ef4[gid];
        uint2 p;
        p.x = f2bf(v.x) | (f2bf(v.y) << 16);
        p.y = f2bf(v.z) | (f2bf(v.w) << 16);
        eb2[gid] = p;
    }
    // u_enc init: 3*768*128 = 294912 over 196608 threads
    u_enc[gid0] = ENC_NEG_INF;
    if (gid0 < 98304) u_enc[196608 + gid0] = ENC_NEG_INF;
    if (gid0 < NN * IND){ int n = gid0 >> 6, c = gid0 & 63; out[n * 256 + c] = states[n * IND + c]; }
    if (gid0 < NN * 2){ int n = gid0 >> 1, cc = gid0 & 1; out[196608 + n * 8 + cc] = 0.f; }
}

// ---------- K2: MFMA msgmax -> atomicMax u_enc[t] (blocks 0..383); msbuf zero + stop(t-1) (384..511) ----------
__global__ __launch_bounds__(256)
void k2_ker(const unsigned short* __restrict__ ebf, const float* __restrict__ zsrc,
            const float* __restrict__ Wm, unsigned* __restrict__ u_enc,
            const float* __restrict__ hid, unsigned long long* __restrict__ msbuf,
            const float* __restrict__ Wt, const float* __restrict__ bt,
            float* __restrict__ out, int t)
{
    int bid = blockIdx.x, tid = threadIdx.x;
    if (bid < 384){
        const float* WmE = Wm + 2 * HD * HD;
        int lane = tid & 63;
        int wv = tid >> 6;
        int jt = bid % 24, ch = bid / 24;
        int j0 = jt * 32, h0 = wv * 32, i0 = ch * CHUNK;
        int ln = lane & 31, lh = lane >> 5;

        short8 b;
        #pragma unroll
        for (int q = 0; q < 8; ++q)
            b[q] = (short)f2bf(WmE[(8 * lh + q) * HD + h0 + ln]);

        floatx16 czero, run;
        #pragma unroll
        for (int r = 0; r < 16; ++r){ czero[r] = 0.f; run[r] = -INFINITY; }

        const unsigned short* abase = ebf + (size_t)(j0 + ln) * EFD + 8 * lh;
        #pragma unroll 2
        for (int ii = 0; ii < CHUNK; ++ii){
            int i = i0 + ii;
            short8 a = *reinterpret_cast<const short8*>(abase + (size_t)i * NN * EFD);
            float zsv = zsrc[i * HD + h0 + ln];
            floatx16 d = __builtin_amdgcn_mfma_f32_32x32x16_bf16(a, b, czero, 0, 0, 0);
            #pragma unroll
            for (int r = 0; r < 16; ++r) run[r] = fmaxf(run[r], d[r] + zsv);
        }
        unsigned* ub = u_enc + t * (NN * HD) + j0 * HD + h0 + ln;
        #pragma unroll
        for (int r = 0; r < 16; ++r){
            int row = (r & 3) + 8 * (r >> 2) + 4 * lh;
            atomicMax(ub + row * HD, enc_f(run[r]));
        }
    } else {
        int b2 = bid - 384;
        if (b2 == 0 && tid < HD) msbuf[(t & 1) * HD + tid] = 0ull;
        if (t > 0 && tid < 12){
            int row = b2 * 6 + (tid >> 1), cc = tid & 1;
            float a2 = bt[cc];
            const float* hrow = hid + row * HD;
            #pragma unroll 8
            for (int k = 0; k < HD; ++k) a2 += hrow[k] * Wt[k * 2 + cc];
            const unsigned long long* msp = msbuf + ((t - 1) & 1) * HD;
            const float sc = 1.0f / (768.0f * 1048576.0f);
            #pragma unroll 8
            for (int k = 0; k < HD; ++k){
                float mk = (float)(long long)msp[k] * sc;
                a2 += mk * Wt[(HD + k) * 2 + cc];
            }
            out[196608 + row * 8 + t * 2 + cc] = 1.f / (1.f + expf(-a2));
        }
    }
}

// ---------- K3: one row per block; K-split float4 phases ----------
// P1: h_new = [z|u]@Wu+bu   P2: state' = [h|z]@Wd+bd   P3: z' = [s'|h]@We+be
// P4: zsrc' = z'@WmS, zdst' = z'@WmD
__global__ __launch_bounds__(256)
void k3_ker(float* __restrict__ z, float* __restrict__ zsrc, float* __restrict__ zdst,
            const unsigned* __restrict__ u_enc, const float* __restrict__ bm,
            const float* __restrict__ Wu, const float* __restrict__ bu,
            const float* __restrict__ Wd, const float* __restrict__ bd,
            const float* __restrict__ We, const float* __restrict__ be,
            const float* __restrict__ Wm,
            float* __restrict__ hid, float* __restrict__ state,
            unsigned long long* __restrict__ msbuf, float* __restrict__ out, int t)
{
    __shared__ float sA[256];    // [z(128) | u(128)]  (P1 source)
    __shared__ float sB[256];    // [h_new(128) | z(128)]  (P2 source)
    __shared__ float sC[192];    // [state'(64) | h_new(128)]  (P3 source)
    __shared__ float sZ2[128];   // z' (P4 source)
    __shared__ float pp[1024];   // partials (8x128 or 16x64)
    __shared__ float ppB[1024];  // partials for zdst

    int m = blockIdx.x, tid = threadIdx.x;

    if (tid < 128){
        float zv = z[m * HD + tid];
        sA[tid] = zv;
        sB[128 + tid] = zv;
    } else {
        int kk = tid - 128;
        sA[tid] = dec_f(u_enc[t * (NN * HD) + m * HD + kk]) + zdst[m * HD + kk] + bm[kk];
    }
    __syncthreads();

    int h4 = tid & 31, ks = tid >> 5;          // 8 slices
    const float4* Wu4 = reinterpret_cast<const float4*>(Wu);
    const float4* Wd4 = reinterpret_cast<const float4*>(Wd);
    const float4* We4 = reinterpret_cast<const float4*>(We);
    const float4* WmS4 = reinterpret_cast<const float4*>(Wm);
    const float4* WmD4 = reinterpret_cast<const float4*>(Wm + HD * HD);

    // ---- P1: h_new, K=256, 8 slices x 32 ----
    {
        float4 a4 = make_float4(0.f, 0.f, 0.f, 0.f);
        #pragma unroll
        for (int kk = 0; kk < 32; ++kk){
            int k = ks * 32 + kk;
            float s = sA[k];
            float4 w = Wu4[k * 32 + h4];
            a4.x += s * w.x; a4.y += s * w.y; a4.z += s * w.z; a4.w += s * w.w;
        }
        *reinterpret_cast<float4*>(&pp[ks * 128 + 4 * h4]) = a4;
    }
    __syncthreads();
    if (tid < 128){
        float acc = bu[tid];
        #pragma unroll
        for (int q = 0; q < 8; ++q) acc += pp[q * 128 + tid];
        hid[m * HD + tid] = acc;
        sB[tid] = acc;
        sC[64 + tid] = acc;
        atomicAdd(&msbuf[(t & 1) * HD + tid],
                  (unsigned long long)(long long)llrintf(acc * 1048576.f));
    }
    __syncthreads();

    // ---- P2: state', K=256 ([h|z]=sB), out 64, 16 slices x 16 ----
    {
        int c4 = tid & 15, ks2 = tid >> 4;
        float4 a4 = make_float4(0.f, 0.f, 0.f, 0.f);
        #pragma unroll
        for (int kk = 0; kk < 16; ++kk){
            int k = ks2 * 16 + kk;
            float s = sB[k];
            float4 w = Wd4[k * 16 + c4];
            a4.x += s * w.x; a4.y += s * w.y; a4.z += s * w.z; a4.w += s * w.w;
        }
        *reinterpret_cast<float4*>(&pp[ks2 * 64 + 4 * c4]) = a4;
    }
    __syncthreads();
    if (tid < 64){
        float acc = bd[tid];
        #pragma unroll
        for (int q = 0; q < 16; ++q) acc += pp[q * 64 + tid];
        state[m * IND + tid] = acc;
        out[m * 256 + (t + 1) * IND + tid] = acc;
        sC[tid] = acc;
    }
    __syncthreads();

    if (t < TT - 1){
        // ---- P3: z', K=192 (sC), 8 slices x 24 ----
        {
            float4 a4 = make_float4(0.f, 0.f, 0.f, 0.f);
            #pragma unroll
            for (int kk = 0; kk < 24; ++kk){
                int k = ks * 24 + kk;
                float s = sC[k];
                float4 w = We4[k * 32 + h4];
                a4.x += s * w.x; a4.y += s * w.y; a4.z += s * w.z; a4.w += s * w.w;
            }
            *reinterpret_cast<float4*>(&pp[ks * 128 + 4 * h4]) = a4;
        }
        __syncthreads();
        if (tid < 128){
            float acc = be[tid];
            #pragma unroll
            for (int q = 0; q < 8; ++q) acc += pp[q * 128 + tid];
            z[m * HD + tid] = acc;
            sZ2[tid] = acc;
        }
        __syncthreads();

        // ---- P4: zsrc'/zdst', K=128 (sZ2), 8 slices x 16 ----
        {
            float4 aS = make_float4(0.f, 0.f, 0.f, 0.f);
            float4 aD = make_float4(0.f, 0.f, 0.f, 0.f);
            #pragma unroll
            for (int kk = 0; kk < 16; ++kk){
                int k = ks * 16 + kk;
                float s = sZ2[k];
                float4 w1 = WmS4[k * 32 + h4];
                float4 w2 = WmD4[k * 32 + h4];
                aS.x += s * w1.x; aS.y += s * w1.y; aS.z += s * w1.z; aS.w += s * w1.w;
                aD.x += s * w2.x; aD.y += s * w2.y; aD.z += s * w2.z; aD.w += s * w2.w;
            }
            *reinterpret_cast<float4*>(&pp[ks * 128 + 4 * h4]) = aS;
            *reinterpret_cast<float4*>(&ppB[ks * 128 + 4 * h4]) = aD;
        }
        __syncthreads();
        if (tid < 128){
            float accS = 0.f, accD = 0.f;
            #pragma unroll
            for (int q = 0; q < 8; ++q){ accS += pp[q * 128 + tid]; accD += ppB[q * 128 + tid]; }
            zsrc[m * HD + tid] = accS;
            zdst[m * HD + tid] = accD;
        }
    }
}

// ---------- final stop (t = TT-1) ----------
__global__ void kstop_ker(const float* __restrict__ hid, const unsigned long long* __restrict__ msbuf,
                          const float* __restrict__ Wt, const float* __restrict__ bt,
                          float* __restrict__ out)
{
    int tid = threadIdx.x;
    if (tid < 12){
        int row = blockIdx.x * 6 + (tid >> 1), cc = tid & 1;
        float a2 = bt[cc];
        const float* hrow = hid + row * HD;
        #pragma unroll 8
        for (int k = 0; k < HD; ++k) a2 += hrow[k] * Wt[k * 2 + cc];
        const unsigned long long* msp = msbuf + ((TT - 1) & 1) * HD;
        const float sc = 1.0f / (768.0f * 1048576.0f);
        #pragma unroll 8
        for (int k = 0; k < HD; ++k){
            float mk = (float)(long long)msp[k] * sc;
            a2 += mk * Wt[(HD + k) * 2 + cc];
        }
        out[196608 + row * 8 + TT * 2 + cc] = 1.f / (1.f + expf(-a2));
    }
}

extern "C" void kernel_launch(void* const* d_in, const int* in_sizes, int n_in,
                              void* d_out, int out_size, void* d_ws, size_t ws_size,
                              hipStream_t stream){
    const float* states = (const float*)d_in[0];
    const float* edges  = (const float*)d_in[1];
    const float* We = (const float*)d_in[2];
    const float* be = (const float*)d_in[3];
    const float* Wm = (const float*)d_in[4];
    const float* bm = (const float*)d_in[5];
    const float* Wu = (const float*)d_in[6];
    const float* bu = (const float*)d_in[7];
    const float* Wd = (const float*)d_in[8];
    const float* bd = (const float*)d_in[9];
    const float* Wt = (const float*)d_in[10];
    const float* bt = (const float*)d_in[11];
    float* out = (float*)d_out;

    float* ws = (float*)d_ws;
    float* z       = ws;                        // 98304
    float* zsrc    = ws + 98304;                // 98304
    float* zdst    = ws + 196608;               // 98304
    float* hid     = ws + 294912;               // 98304
    float* state   = ws + 393216;               // 49152
    unsigned long long* msbuf = (unsigned long long*)(ws + 442368); // 256 ull = 512 f
    unsigned* u_enc = (unsigned*)(ws + 442880); // 3*768*128 = 294912 u32
    unsigned short* ebf = (unsigned short*)(ws + 737792); // 9437184 bf16

    k1_ker<<<768, 256, 0, stream>>>(states, edges, We, be, Wm, out, z, zsrc, zdst, ebf, u_enc);
    for (int t = 0; t < TT; ++t){
        k2_ker<<<512, 256, 0, stream>>>(ebf, zsrc, Wm, u_enc, hid, msbuf, Wt, bt, out, t);
        k3_ker<<<768, 256, 0, stream>>>(z, zsrc, zdst, u_enc, bm, Wu, bu, Wd, bd,
                                        We, be, Wm, hid, state, msbuf, out, t);
    }
    kstop_ker<<<128, 256, 0, stream>>>(hid, msbuf, Wt, bt, out);
}

// Round 11
// 118.951 us; speedup vs baseline: 1.8281x; 1.3279x over previous
//
#include <hip/hip_runtime.h>
#include <cstdint>
#include <cstddef>

#define NN  768
#define IND 64
#define HD  128
#define EFD 16
#define TT  3
#define NC  16      // i-chunks in msgmax
#define CHUNK 48    // 768/NC

typedef __attribute__((ext_vector_type(8)))  short short8;
typedef __attribute__((ext_vector_type(16))) float floatx16;

__device__ __forceinline__ unsigned f2bf(float f){
    unsigned u = __float_as_uint(f);
    return (u + 0x7FFFu + ((u >> 16) & 1u)) >> 16;
}
// monotonic uint encoding of float for atomicMax
__device__ __forceinline__ unsigned enc_f(float f){
    unsigned b = __float_as_uint(f);
    return (b & 0x80000000u) ? ~b : (b | 0x80000000u);
}
__device__ __forceinline__ float dec_f(unsigned e){
    return __uint_as_float((e & 0x80000000u) ? (e & 0x7FFFFFFFu) : ~e);
}
#define ENC_NEG_INF 0x007FFFFFu

// ---------- K1: z(0)+zsrc/zdst(0) row-local; edges f32->bf16; u_enc init; output init ----------
__global__ __launch_bounds__(256)
void k1_ker(const float* __restrict__ states, const float* __restrict__ edges,
            const float* __restrict__ We, const float* __restrict__ be,
            const float* __restrict__ Wm, float* __restrict__ out,
            float* __restrict__ z, float* __restrict__ zsrc, float* __restrict__ zdst,
            unsigned short* __restrict__ ebf, unsigned* __restrict__ u_enc)
{
    int bid = blockIdx.x, tid = threadIdx.x;
    __shared__ float sZ[HD];
    if (tid < HD){
        float acc = be[tid];
        const float* srow = states + bid * IND;
        #pragma unroll
        for (int k = 0; k < IND; ++k) acc += srow[k] * We[k * HD + tid];
        z[bid * HD + tid] = acc;
        sZ[tid] = acc;
    }
    __syncthreads();
    {
        int h = tid & 127, which = tid >> 7;
        const float* W = Wm + which * HD * HD;
        float acc = 0.f;
        #pragma unroll 8
        for (int k = 0; k < HD; ++k) acc += sZ[k] * W[k * HD + h];
        (which ? zdst : zsrc)[bid * HD + h] = acc;
    }
    // edges conv: 2359296 float4 over 768*256 threads = 12 iters
    const float4* ef4 = reinterpret_cast<const float4*>(edges);
    uint2* eb2 = reinterpret_cast<uint2*>(ebf);
    int gid0 = bid * 256 + tid;
    for (int it = 0; it < 12; ++it){
        int gid = gid0 + it * 196608;
        float4 v = ef4[gid];
        uint2 p;
        p.x = f2bf(v.x) | (f2bf(v.y) << 16);
        p.y = f2bf(v.z) | (f2bf(v.w) << 16);
        eb2[gid] = p;
    }
    // u_enc init: 3*768*128 = 294912 over 196608 threads
    u_enc[gid0] = ENC_NEG_INF;
    if (gid0 < 98304) u_enc[196608 + gid0] = ENC_NEG_INF;
    if (gid0 < NN * IND){ int n = gid0 >> 6, c = gid0 & 63; out[n * 256 + c] = states[n * IND + c]; }
    if (gid0 < NN * 2){ int n = gid0 >> 1, cc = gid0 & 1; out[196608 + n * 8 + cc] = 0.f; }
}

// ---------- K2: MFMA msgmax -> atomicMax u_enc[t] (blocks 0..383); msbuf zero + stop(t-1) (384..511) ----------
__global__ __launch_bounds__(256)
void k2_ker(const unsigned short* __restrict__ ebf, const float* __restrict__ zsrc,
            const float* __restrict__ Wm, unsigned* __restrict__ u_enc,
            const float* __restrict__ hid, unsigned long long* __restrict__ msbuf,
            const float* __restrict__ Wt, const float* __restrict__ bt,
            float* __restrict__ out, int t)
{
    int bid = blockIdx.x, tid = threadIdx.x;
    if (bid < 384){
        const float* WmE = Wm + 2 * HD * HD;
        int lane = tid & 63;
        int wv = tid >> 6;
        int jt = bid % 24, ch = bid / 24;
        int j0 = jt * 32, h0 = wv * 32, i0 = ch * CHUNK;
        int ln = lane & 31, lh = lane >> 5;

        short8 b;
        #pragma unroll
        for (int q = 0; q < 8; ++q)
            b[q] = (short)f2bf(WmE[(8 * lh + q) * HD + h0 + ln]);

        floatx16 czero, run;
        #pragma unroll
        for (int r = 0; r < 16; ++r){ czero[r] = 0.f; run[r] = -INFINITY; }

        const unsigned short* abase = ebf + (size_t)(j0 + ln) * EFD + 8 * lh;
        #pragma unroll 2
        for (int ii = 0; ii < CHUNK; ++ii){
            int i = i0 + ii;
            short8 a = *reinterpret_cast<const short8*>(abase + (size_t)i * NN * EFD);
            float zsv = zsrc[i * HD + h0 + ln];
            floatx16 d = __builtin_amdgcn_mfma_f32_32x32x16_bf16(a, b, czero, 0, 0, 0);
            #pragma unroll
            for (int r = 0; r < 16; ++r) run[r] = fmaxf(run[r], d[r] + zsv);
        }
        unsigned* ub = u_enc + t * (NN * HD) + j0 * HD + h0 + ln;
        #pragma unroll
        for (int r = 0; r < 16; ++r){
            int row = (r & 3) + 8 * (r >> 2) + 4 * lh;
            atomicMax(ub + row * HD, enc_f(run[r]));
        }
    } else {
        int b2 = bid - 384;
        if (b2 == 0 && tid < HD) msbuf[(t & 1) * HD + tid] = 0ull;
        if (t > 0 && tid < 12){
            int row = b2 * 6 + (tid >> 1), cc = tid & 1;
            float a2 = bt[cc];
            const float* hrow = hid + row * HD;
            #pragma unroll 8
            for (int k = 0; k < HD; ++k) a2 += hrow[k] * Wt[k * 2 + cc];
            const unsigned long long* msp = msbuf + ((t - 1) & 1) * HD;
            const float sc = 1.0f / (768.0f * 1048576.0f);
            #pragma unroll 8
            for (int k = 0; k < HD; ++k){
                float mk = (float)(long long)msp[k] * sc;
                a2 += mk * Wt[(HD + k) * 2 + cc];
            }
            out[196608 + row * 8 + t * 2 + cc] = 1.f / (1.f + expf(-a2));
        }
    }
}

// ---------- K3 v4: 3 rows/block, 512 threads; per-phase (h4, ksl) split; LDS partial reduce ----------
// P1: h_new=[z|u]@Wu+bu  P2: state'=[h|z]@Wd+bd  P3: z'=[s'|h]@We+be  P4: zsrc/zdst=z'@WmS/WmD
__global__ __launch_bounds__(512)
void k3_ker(float* __restrict__ z, float* __restrict__ zsrc, float* __restrict__ zdst,
            const unsigned* __restrict__ u_enc, const float* __restrict__ bm,
            const float* __restrict__ Wu, const float* __restrict__ bu,
            const float* __restrict__ Wd, const float* __restrict__ bd,
            const float* __restrict__ We, const float* __restrict__ be,
            const float* __restrict__ Wm,
            float* __restrict__ hid, float* __restrict__ state,
            unsigned long long* __restrict__ msbuf, float* __restrict__ out, int t)
{
    __shared__ float sA[3][256];   // [z(128)|u(128)]
    __shared__ float sB[3][256];   // [h_new|z]
    __shared__ float sC[3][192];   // [state'|h_new]
    __shared__ float sH[3][128];   // h_new
    __shared__ float sZ2[3][128];  // z'
    __shared__ float pp[6144];     // partials
    __shared__ float ppB[6144];    // partials (zdst)

    int tid = threadIdx.x;
    int m0 = blockIdx.x * 3;

    const float4* Wu4  = reinterpret_cast<const float4*>(Wu);
    const float4* Wd4  = reinterpret_cast<const float4*>(Wd);
    const float4* We4  = reinterpret_cast<const float4*>(We);
    const float4* WmS4 = reinterpret_cast<const float4*>(Wm);
    const float4* WmD4 = reinterpret_cast<const float4*>(Wm + HD * HD);

    // ---- inputs: 3*256 values ----
    for (int i = tid; i < 768; i += 512){
        int r = i >> 8, k = i & 255;
        float v;
        if (k < HD) v = z[(m0 + r) * HD + k];
        else {
            int kk = k - HD;
            v = dec_f(u_enc[t * (NN * HD) + (m0 + r) * HD + kk]) + zdst[(m0 + r) * HD + kk] + bm[kk];
        }
        sA[r][k] = v;
    }
    __syncthreads();

    int h4 = tid & 31, ksl = tid >> 5;      // 16 K-slices (P1/P3/P4)
    int c4 = tid & 15, ksl2 = tid >> 4;     // 32 K-slices (P2)

    // ---- P1 partials: K=256 = 16 slices x 16 ----
    {
        float4 a0 = make_float4(0,0,0,0), a1 = a0, a2 = a0;
        #pragma unroll
        for (int kk = 0; kk < 16; ++kk){
            int k = ksl * 16 + kk;
            float4 w = Wu4[k * 32 + h4];
            float s0 = sA[0][k], s1 = sA[1][k], s2 = sA[2][k];
            a0.x += s0*w.x; a0.y += s0*w.y; a0.z += s0*w.z; a0.w += s0*w.w;
            a1.x += s1*w.x; a1.y += s1*w.y; a1.z += s1*w.z; a1.w += s1*w.w;
            a2.x += s2*w.x; a2.y += s2*w.y; a2.z += s2*w.z; a2.w += s2*w.w;
        }
        *reinterpret_cast<float4*>(&pp[(ksl * 3 + 0) * 128 + 4 * h4]) = a0;
        *reinterpret_cast<float4*>(&pp[(ksl * 3 + 1) * 128 + 4 * h4]) = a1;
        *reinterpret_cast<float4*>(&pp[(ksl * 3 + 2) * 128 + 4 * h4]) = a2;
    }
    __syncthreads();
    // ---- P1 reduce ----
    if (tid < 384){
        int r = tid >> 7, h = tid & 127;
        float acc = bu[h];
        #pragma unroll
        for (int q = 0; q < 16; ++q) acc += pp[(q * 3 + r) * 128 + h];
        hid[(m0 + r) * HD + h] = acc;
        sH[r][h] = acc;
        sB[r][h] = acc;
        sB[r][128 + h] = sA[r][h];
    }
    __syncthreads();
    if (tid < 128){
        long long s = llrintf(sH[0][tid] * 1048576.f) + llrintf(sH[1][tid] * 1048576.f)
                    + llrintf(sH[2][tid] * 1048576.f);
        atomicAdd(&msbuf[(t & 1) * HD + tid], (unsigned long long)s);
    }
    if (tid < 384){
        int r = tid >> 7, h = tid & 127;
        sC[r][64 + h] = sH[r][h];
    }

    // ---- P2 partials: K=256 = 32 slices x 8, out 64 ----
    {
        float4 a0 = make_float4(0,0,0,0), a1 = a0, a2 = a0;
        #pragma unroll
        for (int kk = 0; kk < 8; ++kk){
            int k = ksl2 * 8 + kk;
            float4 w = Wd4[k * 16 + c4];
            float s0 = sB[0][k], s1 = sB[1][k], s2 = sB[2][k];
            a0.x += s0*w.x; a0.y += s0*w.y; a0.z += s0*w.z; a0.w += s0*w.w;
            a1.x += s1*w.x; a1.y += s1*w.y; a1.z += s1*w.z; a1.w += s1*w.w;
            a2.x += s2*w.x; a2.y += s2*w.y; a2.z += s2*w.z; a2.w += s2*w.w;
        }
        *reinterpret_cast<float4*>(&pp[(ksl2 * 3 + 0) * 64 + 4 * c4]) = a0;
        *reinterpret_cast<float4*>(&pp[(ksl2 * 3 + 1) * 64 + 4 * c4]) = a1;
        *reinterpret_cast<float4*>(&pp[(ksl2 * 3 + 2) * 64 + 4 * c4]) = a2;
    }
    __syncthreads();
    // ---- P2 reduce ----
    if (tid < 192){
        int r = tid >> 6, c = tid & 63;
        float acc = bd[c];
        #pragma unroll
        for (int q = 0; q < 32; ++q) acc += pp[(q * 3 + r) * 64 + c];
        state[(m0 + r) * IND + c] = acc;
        out[(m0 + r) * 256 + (t + 1) * IND + c] = acc;
        sC[r][c] = acc;
    }
    __syncthreads();

    if (t < TT - 1){
        // ---- P3 partials: K=192 = 16 slices x 12 ----
        {
            float4 a0 = make_float4(0,0,0,0), a1 = a0, a2 = a0;
            #pragma unroll
            for (int kk = 0; kk < 12; ++kk){
                int k = ksl * 12 + kk;
                float4 w = We4[k * 32 + h4];
                float s0 = sC[0][k], s1 = sC[1][k], s2 = sC[2][k];
                a0.x += s0*w.x; a0.y += s0*w.y; a0.z += s0*w.z; a0.w += s0*w.w;
                a1.x += s1*w.x; a1.y += s1*w.y; a1.z += s1*w.z; a1.w += s1*w.w;
                a2.x += s2*w.x; a2.y += s2*w.y; a2.z += s2*w.z; a2.w += s2*w.w;
            }
            *reinterpret_cast<float4*>(&pp[(ksl * 3 + 0) * 128 + 4 * h4]) = a0;
            *reinterpret_cast<float4*>(&pp[(ksl * 3 + 1) * 128 + 4 * h4]) = a1;
            *reinterpret_cast<float4*>(&pp[(ksl * 3 + 2) * 128 + 4 * h4]) = a2;
        }
        __syncthreads();
        if (tid < 384){
            int r = tid >> 7, h = tid & 127;
            float acc = be[h];
            #pragma unroll
            for (int q = 0; q < 16; ++q) acc += pp[(q * 3 + r) * 128 + h];
            z[(m0 + r) * HD + h] = acc;
            sZ2[r][h] = acc;
        }
        __syncthreads();

        // ---- P4 partials: K=128 = 16 slices x 8, two outputs ----
        {
            float4 a0 = make_float4(0,0,0,0), a1 = a0, a2 = a0;
            float4 b0 = a0, b1 = a0, b2 = a0;
            #pragma unroll
            for (int kk = 0; kk < 8; ++kk){
                int k = ksl * 8 + kk;
                float4 wS = WmS4[k * 32 + h4];
                float4 wD = WmD4[k * 32 + h4];
                float s0 = sZ2[0][k], s1 = sZ2[1][k], s2 = sZ2[2][k];
                a0.x += s0*wS.x; a0.y += s0*wS.y; a0.z += s0*wS.z; a0.w += s0*wS.w;
                a1.x += s1*wS.x; a1.y += s1*wS.y; a1.z += s1*wS.z; a1.w += s1*wS.w;
                a2.x += s2*wS.x; a2.y += s2*wS.y; a2.z += s2*wS.z; a2.w += s2*wS.w;
                b0.x += s0*wD.x; b0.y += s0*wD.y; b0.z += s0*wD.z; b0.w += s0*wD.w;
                b1.x += s1*wD.x; b1.y += s1*wD.y; b1.z += s1*wD.z; b1.w += s1*wD.w;
                b2.x += s2*wD.x; b2.y += s2*wD.y; b2.z += s2*wD.z; b2.w += s2*wD.w;
            }
            *reinterpret_cast<float4*>(&pp[(ksl * 3 + 0) * 128 + 4 * h4]) = a0;
            *reinterpret_cast<float4*>(&pp[(ksl * 3 + 1) * 128 + 4 * h4]) = a1;
            *reinterpret_cast<float4*>(&pp[(ksl * 3 + 2) * 128 + 4 * h4]) = a2;
            *reinterpret_cast<float4*>(&ppB[(ksl * 3 + 0) * 128 + 4 * h4]) = b0;
            *reinterpret_cast<float4*>(&ppB[(ksl * 3 + 1) * 128 + 4 * h4]) = b1;
            *reinterpret_cast<float4*>(&ppB[(ksl * 3 + 2) * 128 + 4 * h4]) = b2;
        }
        __syncthreads();
        if (tid < 384){
            int r = tid >> 7, h = tid & 127;
            float accS = 0.f, accD = 0.f;
            #pragma unroll
            for (int q = 0; q < 16; ++q){
                accS += pp[(q * 3 + r) * 128 + h];
                accD += ppB[(q * 3 + r) * 128 + h];
            }
            zsrc[(m0 + r) * HD + h] = accS;
            zdst[(m0 + r) * HD + h] = accD;
        }
    }
}

// ---------- final stop (t = TT-1) ----------
__global__ void kstop_ker(const float* __restrict__ hid, const unsigned long long* __restrict__ msbuf,
                          const float* __restrict__ Wt, const float* __restrict__ bt,
                          float* __restrict__ out)
{
    int tid = threadIdx.x;
    if (tid < 12){
        int row = blockIdx.x * 6 + (tid >> 1), cc = tid & 1;
        float a2 = bt[cc];
        const float* hrow = hid + row * HD;
        #pragma unroll 8
        for (int k = 0; k < HD; ++k) a2 += hrow[k] * Wt[k * 2 + cc];
        const unsigned long long* msp = msbuf + ((TT - 1) & 1) * HD;
        const float sc = 1.0f / (768.0f * 1048576.0f);
        #pragma unroll 8
        for (int k = 0; k < HD; ++k){
            float mk = (float)(long long)msp[k] * sc;
            a2 += mk * Wt[(HD + k) * 2 + cc];
        }
        out[196608 + row * 8 + TT * 2 + cc] = 1.f / (1.f + expf(-a2));
    }
}

extern "C" void kernel_launch(void* const* d_in, const int* in_sizes, int n_in,
                              void* d_out, int out_size, void* d_ws, size_t ws_size,
                              hipStream_t stream){
    const float* states = (const float*)d_in[0];
    const float* edges  = (const float*)d_in[1];
    const float* We = (const float*)d_in[2];
    const float* be = (const float*)d_in[3];
    const float* Wm = (const float*)d_in[4];
    const float* bm = (const float*)d_in[5];
    const float* Wu = (const float*)d_in[6];
    const float* bu = (const float*)d_in[7];
    const float* Wd = (const float*)d_in[8];
    const float* bd = (const float*)d_in[9];
    const float* Wt = (const float*)d_in[10];
    const float* bt = (const float*)d_in[11];
    float* out = (float*)d_out;

    float* ws = (float*)d_ws;
    float* z       = ws;                        // 98304
    float* zsrc    = ws + 98304;                // 98304
    float* zdst    = ws + 196608;               // 98304
    float* hid     = ws + 294912;               // 98304
    float* state   = ws + 393216;               // 49152
    unsigned long long* msbuf = (unsigned long long*)(ws + 442368); // 256 ull = 512 f
    unsigned* u_enc = (unsigned*)(ws + 442880); // 3*768*128 = 294912 u32
    unsigned short* ebf = (unsigned short*)(ws + 737792); // 9437184 bf16

    k1_ker<<<768, 256, 0, stream>>>(states, edges, We, be, Wm, out, z, zsrc, zdst, ebf, u_enc);
    for (int t = 0; t < TT; ++t){
        k2_ker<<<512, 256, 0, stream>>>(ebf, zsrc, Wm, u_enc, hid, msbuf, Wt, bt, out, t);
        k3_ker<<<256, 512, 0, stream>>>(z, zsrc, zdst, u_enc, bm, Wu, bu, Wd, bd,
                                        We, be, Wm, hid, state, msbuf, out, t);
    }
    kstop_ker<<<128, 256, 0, stream>>>(hid, msbuf, Wt, bt, out);
}

// Round 12
// 114.431 us; speedup vs baseline: 1.9003x; 1.0395x over previous
//
#include <hip/hip_runtime.h>
#include <cstdint>
#include <cstddef>

#define NN  768
#define IND 64
#define HD  128
#define EFD 16
#define TT  3
#define NC  16      // i-chunks in msgmax
#define CHUNK 48    // 768/NC

typedef __attribute__((ext_vector_type(8)))  short short8;
typedef __attribute__((ext_vector_type(16))) float floatx16;

__device__ __forceinline__ unsigned f2bf(float f){
    unsigned u = __float_as_uint(f);
    return (u + 0x7FFFu + ((u >> 16) & 1u)) >> 16;
}
// monotonic uint encoding of float for atomicMax
__device__ __forceinline__ unsigned enc_f(float f){
    unsigned b = __float_as_uint(f);
    return (b & 0x80000000u) ? ~b : (b | 0x80000000u);
}
__device__ __forceinline__ float dec_f(unsigned e){
    return __uint_as_float((e & 0x80000000u) ? (e & 0x7FFFFFFFu) : ~e);
}
#define ENC_NEG_INF 0x007FFFFFu

// ---------- K1: z(0)+zsrc/zdst(0) row-local; edges f32->bf16; u_enc init; output init ----------
__global__ __launch_bounds__(256)
void k1_ker(const float* __restrict__ states, const float* __restrict__ edges,
            const float* __restrict__ We, const float* __restrict__ be,
            const float* __restrict__ Wm, float* __restrict__ out,
            float* __restrict__ z, float* __restrict__ zsrc, float* __restrict__ zdst,
            unsigned short* __restrict__ ebf, unsigned* __restrict__ u_enc)
{
    int bid = blockIdx.x, tid = threadIdx.x;
    __shared__ float sZ[HD];
    if (tid < HD){
        float acc = be[tid];
        const float* srow = states + bid * IND;
        #pragma unroll
        for (int k = 0; k < IND; ++k) acc += srow[k] * We[k * HD + tid];
        z[bid * HD + tid] = acc;
        sZ[tid] = acc;
    }
    __syncthreads();
    {
        int h = tid & 127, which = tid >> 7;
        const float* W = Wm + which * HD * HD;
        float acc = 0.f;
        #pragma unroll 8
        for (int k = 0; k < HD; ++k) acc += sZ[k] * W[k * HD + h];
        (which ? zdst : zsrc)[bid * HD + h] = acc;
    }
    // edges conv: 2359296 float4 over 768*256 threads = 12 iters
    const float4* ef4 = reinterpret_cast<const float4*>(edges);
    uint2* eb2 = reinterpret_cast<uint2*>(ebf);
    int gid0 = bid * 256 + tid;
    for (int it = 0; it < 12; ++it){
        int gid = gid0 + it * 196608;
        float4 v = ef4[gid];
        uint2 p;
        p.x = f2bf(v.x) | (f2bf(v.y) << 16);
        p.y = f2bf(v.z) | (f2bf(v.w) << 16);
        eb2[gid] = p;
    }
    // u_enc init: 3*768*128 = 294912 over 196608 threads
    u_enc[gid0] = ENC_NEG_INF;
    if (gid0 < 98304) u_enc[196608 + gid0] = ENC_NEG_INF;
    if (gid0 < NN * IND){ int n = gid0 >> 6, c = gid0 & 63; out[n * 256 + c] = states[n * IND + c]; }
    if (gid0 < NN * 2){ int n = gid0 >> 1, cc = gid0 & 1; out[196608 + n * 8 + cc] = 0.f; }
}

// ---------- K2: MFMA msgmax -> atomicMax u_enc[t] (blocks 0..383); msbuf zero + stop(t-1) (384..511) ----------
__global__ __launch_bounds__(256)
void k2_ker(const unsigned short* __restrict__ ebf, const float* __restrict__ zsrc,
            const float* __restrict__ Wm, unsigned* __restrict__ u_enc,
            const float* __restrict__ hid, unsigned long long* __restrict__ msbuf,
            const float* __restrict__ Wt, const float* __restrict__ bt,
            float* __restrict__ out, int t)
{
    int bid = blockIdx.x, tid = threadIdx.x;
    if (bid < 384){
        const float* WmE = Wm + 2 * HD * HD;
        int lane = tid & 63;
        int wv = tid >> 6;
        int jt = bid % 24, ch = bid / 24;
        int j0 = jt * 32, h0 = wv * 32, i0 = ch * CHUNK;
        int ln = lane & 31, lh = lane >> 5;

        short8 b;
        #pragma unroll
        for (int q = 0; q < 8; ++q)
            b[q] = (short)f2bf(WmE[(8 * lh + q) * HD + h0 + ln]);

        floatx16 czero, run;
        #pragma unroll
        for (int r = 0; r < 16; ++r){ czero[r] = 0.f; run[r] = -INFINITY; }

        const unsigned short* abase = ebf + (size_t)(j0 + ln) * EFD + 8 * lh;
        #pragma unroll 2
        for (int ii = 0; ii < CHUNK; ++ii){
            int i = i0 + ii;
            short8 a = *reinterpret_cast<const short8*>(abase + (size_t)i * NN * EFD);
            float zsv = zsrc[i * HD + h0 + ln];
            floatx16 d = __builtin_amdgcn_mfma_f32_32x32x16_bf16(a, b, czero, 0, 0, 0);
            #pragma unroll
            for (int r = 0; r < 16; ++r) run[r] = fmaxf(run[r], d[r] + zsv);
        }
        unsigned* ub = u_enc + t * (NN * HD) + j0 * HD + h0 + ln;
        #pragma unroll
        for (int r = 0; r < 16; ++r){
            int row = (r & 3) + 8 * (r >> 2) + 4 * lh;
            atomicMax(ub + row * HD, enc_f(run[r]));
        }
    } else {
        int b2 = bid - 384;
        if (b2 == 0 && tid < HD) msbuf[(t & 1) * HD + tid] = 0ull;
        if (t > 0 && tid < 12){
            int row = b2 * 6 + (tid >> 1), cc = tid & 1;
            float a2 = bt[cc];
            const float* hrow = hid + row * HD;
            #pragma unroll 8
            for (int k = 0; k < HD; ++k) a2 += hrow[k] * Wt[k * 2 + cc];
            const unsigned long long* msp = msbuf + ((t - 1) & 1) * HD;
            const float sc = 1.0f / (768.0f * 1048576.0f);
            #pragma unroll 8
            for (int k = 0; k < HD; ++k){
                float mk = (float)(long long)msp[k] * sc;
                a2 += mk * Wt[(HD + k) * 2 + cc];
            }
            out[196608 + row * 8 + t * 2 + cc] = 1.f / (1.f + expf(-a2));
        }
    }
}

// ---------- K3 v5: 6 rows/block, 128 blocks, 512 threads; weight float4 loaded once, reused x6 rows ----------
// P1: h_new=[z|u]@Wu+bu  P2: state'=[h|z]@Wd+bd  P3: z'=[s'|h]@We+be  P4: zsrc/zdst=z'@WmS/WmD
__global__ __launch_bounds__(512)
void k3_ker(float* __restrict__ z, float* __restrict__ zsrc, float* __restrict__ zdst,
            const unsigned* __restrict__ u_enc, const float* __restrict__ bm,
            const float* __restrict__ Wu, const float* __restrict__ bu,
            const float* __restrict__ Wd, const float* __restrict__ bd,
            const float* __restrict__ We, const float* __restrict__ be,
            const float* __restrict__ Wm,
            float* __restrict__ hid, float* __restrict__ state,
            unsigned long long* __restrict__ msbuf, float* __restrict__ out, int t)
{
    __shared__ float sA[6][256];    // [z(128)|u(128)]
    __shared__ float sB[6][256];    // [h_new|z]
    __shared__ float sC[6][192];    // [state'|h_new]
    __shared__ float sH[6][128];    // h_new
    __shared__ float sZ2[6][128];   // z'
    __shared__ float pp[16][6][128]; // 48 KB partials (P2 views flat as [32][6][64])

    int tid = threadIdx.x;
    int m0 = blockIdx.x * 6;

    const float4* Wu4  = reinterpret_cast<const float4*>(Wu);
    const float4* Wd4  = reinterpret_cast<const float4*>(Wd);
    const float4* We4  = reinterpret_cast<const float4*>(We);
    const float4* WmS4 = reinterpret_cast<const float4*>(Wm);
    const float4* WmD4 = reinterpret_cast<const float4*>(Wm + HD * HD);
    float* ppf = &pp[0][0][0];

    // ---- inputs: 6*256 values ----
    for (int i = tid; i < 1536; i += 512){
        int r = i >> 8, k = i & 255;
        float v;
        if (k < HD) v = z[(m0 + r) * HD + k];
        else {
            int kk = k - HD;
            v = dec_f(u_enc[t * (NN * HD) + (m0 + r) * HD + kk]) + zdst[(m0 + r) * HD + kk] + bm[kk];
        }
        sA[r][k] = v;
    }
    __syncthreads();

    int h4 = tid & 31, ksl = tid >> 5;     // 16 K-slices (P1/P3/P4)
    int c4 = tid & 15, ksl2 = tid >> 4;    // 32 K-slices (P2)

    // ---- P1 partials: K=256 = 16 slices x 16; each weight float4 reused for 6 rows ----
    {
        float4 a0 = make_float4(0,0,0,0), a1 = a0, a2 = a0, a3 = a0, a4 = a0, a5 = a0;
        #pragma unroll
        for (int kk = 0; kk < 16; ++kk){
            int k = ksl * 16 + kk;
            float4 w = Wu4[k * 32 + h4];
            float s0 = sA[0][k], s1 = sA[1][k], s2 = sA[2][k];
            float s3 = sA[3][k], s4 = sA[4][k], s5 = sA[5][k];
            a0.x += s0*w.x; a0.y += s0*w.y; a0.z += s0*w.z; a0.w += s0*w.w;
            a1.x += s1*w.x; a1.y += s1*w.y; a1.z += s1*w.z; a1.w += s1*w.w;
            a2.x += s2*w.x; a2.y += s2*w.y; a2.z += s2*w.z; a2.w += s2*w.w;
            a3.x += s3*w.x; a3.y += s3*w.y; a3.z += s3*w.z; a3.w += s3*w.w;
            a4.x += s4*w.x; a4.y += s4*w.y; a4.z += s4*w.z; a4.w += s4*w.w;
            a5.x += s5*w.x; a5.y += s5*w.y; a5.z += s5*w.z; a5.w += s5*w.w;
        }
        *reinterpret_cast<float4*>(&pp[ksl][0][4*h4]) = a0;
        *reinterpret_cast<float4*>(&pp[ksl][1][4*h4]) = a1;
        *reinterpret_cast<float4*>(&pp[ksl][2][4*h4]) = a2;
        *reinterpret_cast<float4*>(&pp[ksl][3][4*h4]) = a3;
        *reinterpret_cast<float4*>(&pp[ksl][4][4*h4]) = a4;
        *reinterpret_cast<float4*>(&pp[ksl][5][4*h4]) = a5;
    }
    __syncthreads();
    // ---- P1 reduce ----
    for (int i = tid; i < 768; i += 512){
        int r = i >> 7, h = i & 127;
        float acc = bu[h];
        #pragma unroll
        for (int q = 0; q < 16; ++q) acc += pp[q][r][h];
        hid[(m0 + r) * HD + h] = acc;
        sH[r][h] = acc;
        sB[r][h] = acc;
        sB[r][128 + h] = sA[r][h];
        sC[r][64 + h] = acc;
    }
    __syncthreads();
    if (tid < 128){
        long long s = 0;
        #pragma unroll
        for (int r = 0; r < 6; ++r) s += llrintf(sH[r][tid] * 1048576.f);
        atomicAdd(&msbuf[(t & 1) * HD + tid], (unsigned long long)s);
    }

    // ---- P2 partials: K=256 = 32 slices x 8, out 64 ----
    {
        float4 a0 = make_float4(0,0,0,0), a1 = a0, a2 = a0, a3 = a0, a4 = a0, a5 = a0;
        #pragma unroll
        for (int kk = 0; kk < 8; ++kk){
            int k = ksl2 * 8 + kk;
            float4 w = Wd4[k * 16 + c4];
            float s0 = sB[0][k], s1 = sB[1][k], s2 = sB[2][k];
            float s3 = sB[3][k], s4 = sB[4][k], s5 = sB[5][k];
            a0.x += s0*w.x; a0.y += s0*w.y; a0.z += s0*w.z; a0.w += s0*w.w;
            a1.x += s1*w.x; a1.y += s1*w.y; a1.z += s1*w.z; a1.w += s1*w.w;
            a2.x += s2*w.x; a2.y += s2*w.y; a2.z += s2*w.z; a2.w += s2*w.w;
            a3.x += s3*w.x; a3.y += s3*w.y; a3.z += s3*w.z; a3.w += s3*w.w;
            a4.x += s4*w.x; a4.y += s4*w.y; a4.z += s4*w.z; a4.w += s4*w.w;
            a5.x += s5*w.x; a5.y += s5*w.y; a5.z += s5*w.z; a5.w += s5*w.w;
        }
        *reinterpret_cast<float4*>(&ppf[(ksl2*6 + 0)*64 + 4*c4]) = a0;
        *reinterpret_cast<float4*>(&ppf[(ksl2*6 + 1)*64 + 4*c4]) = a1;
        *reinterpret_cast<float4*>(&ppf[(ksl2*6 + 2)*64 + 4*c4]) = a2;
        *reinterpret_cast<float4*>(&ppf[(ksl2*6 + 3)*64 + 4*c4]) = a3;
        *reinterpret_cast<float4*>(&ppf[(ksl2*6 + 4)*64 + 4*c4]) = a4;
        *reinterpret_cast<float4*>(&ppf[(ksl2*6 + 5)*64 + 4*c4]) = a5;
    }
    __syncthreads();
    // ---- P2 reduce ----
    if (tid < 384){
        int r = tid >> 6, c = tid & 63;
        float acc = bd[c];
        #pragma unroll
        for (int q = 0; q < 32; ++q) acc += ppf[(q*6 + r)*64 + c];
        state[(m0 + r) * IND + c] = acc;
        out[(m0 + r) * 256 + (t + 1) * IND + c] = acc;
        sC[r][c] = acc;
    }
    __syncthreads();

    if (t < TT - 1){
        // ---- P3 partials: K=192 = 16 slices x 12 ----
        {
            float4 a0 = make_float4(0,0,0,0), a1 = a0, a2 = a0, a3 = a0, a4 = a0, a5 = a0;
            #pragma unroll
            for (int kk = 0; kk < 12; ++kk){
                int k = ksl * 12 + kk;
                float4 w = We4[k * 32 + h4];
                float s0 = sC[0][k], s1 = sC[1][k], s2 = sC[2][k];
                float s3 = sC[3][k], s4 = sC[4][k], s5 = sC[5][k];
                a0.x += s0*w.x; a0.y += s0*w.y; a0.z += s0*w.z; a0.w += s0*w.w;
                a1.x += s1*w.x; a1.y += s1*w.y; a1.z += s1*w.z; a1.w += s1*w.w;
                a2.x += s2*w.x; a2.y += s2*w.y; a2.z += s2*w.z; a2.w += s2*w.w;
                a3.x += s3*w.x; a3.y += s3*w.y; a3.z += s3*w.z; a3.w += s3*w.w;
                a4.x += s4*w.x; a4.y += s4*w.y; a4.z += s4*w.z; a4.w += s4*w.w;
                a5.x += s5*w.x; a5.y += s5*w.y; a5.z += s5*w.z; a5.w += s5*w.w;
            }
            *reinterpret_cast<float4*>(&pp[ksl][0][4*h4]) = a0;
            *reinterpret_cast<float4*>(&pp[ksl][1][4*h4]) = a1;
            *reinterpret_cast<float4*>(&pp[ksl][2][4*h4]) = a2;
            *reinterpret_cast<float4*>(&pp[ksl][3][4*h4]) = a3;
            *reinterpret_cast<float4*>(&pp[ksl][4][4*h4]) = a4;
            *reinterpret_cast<float4*>(&pp[ksl][5][4*h4]) = a5;
        }
        __syncthreads();
        for (int i = tid; i < 768; i += 512){
            int r = i >> 7, h = i & 127;
            float acc = be[h];
            #pragma unroll
            for (int q = 0; q < 16; ++q) acc += pp[q][r][h];
            z[(m0 + r) * HD + h] = acc;
            sZ2[r][h] = acc;
        }
        __syncthreads();

        // ---- P4: K=128 = 16 slices x 8, both mats in one pass ----
        float4 aS0 = make_float4(0,0,0,0), aS1 = aS0, aS2 = aS0, aS3 = aS0, aS4 = aS0, aS5 = aS0;
        float4 aD0 = aS0, aD1 = aS0, aD2 = aS0, aD3 = aS0, aD4 = aS0, aD5 = aS0;
        #pragma unroll
        for (int kk = 0; kk < 8; ++kk){
            int k = ksl * 8 + kk;
            float4 wS = WmS4[k * 32 + h4];
            float4 wD = WmD4[k * 32 + h4];
            float s0 = sZ2[0][k], s1 = sZ2[1][k], s2 = sZ2[2][k];
            float s3 = sZ2[3][k], s4 = sZ2[4][k], s5 = sZ2[5][k];
            aS0.x += s0*wS.x; aS0.y += s0*wS.y; aS0.z += s0*wS.z; aS0.w += s0*wS.w;
            aS1.x += s1*wS.x; aS1.y += s1*wS.y; aS1.z += s1*wS.z; aS1.w += s1*wS.w;
            aS2.x += s2*wS.x; aS2.y += s2*wS.y; aS2.z += s2*wS.z; aS2.w += s2*wS.w;
            aS3.x += s3*wS.x; aS3.y += s3*wS.y; aS3.z += s3*wS.z; aS3.w += s3*wS.w;
            aS4.x += s4*wS.x; aS4.y += s4*wS.y; aS4.z += s4*wS.z; aS4.w += s4*wS.w;
            aS5.x += s5*wS.x; aS5.y += s5*wS.y; aS5.z += s5*wS.z; aS5.w += s5*wS.w;
            aD0.x += s0*wD.x; aD0.y += s0*wD.y; aD0.z += s0*wD.z; aD0.w += s0*wD.w;
            aD1.x += s1*wD.x; aD1.y += s1*wD.y; aD1.z += s1*wD.z; aD1.w += s1*wD.w;
            aD2.x += s2*wD.x; aD2.y += s2*wD.y; aD2.z += s2*wD.z; aD2.w += s2*wD.w;
            aD3.x += s3*wD.x; aD3.y += s3*wD.y; aD3.z += s3*wD.z; aD3.w += s3*wD.w;
            aD4.x += s4*wD.x; aD4.y += s4*wD.y; aD4.z += s4*wD.z; aD4.w += s4*wD.w;
            aD5.x += s5*wD.x; aD5.y += s5*wD.y; aD5.z += s5*wD.z; aD5.w += s5*wD.w;
        }
        *reinterpret_cast<float4*>(&pp[ksl][0][4*h4]) = aS0;
        *reinterpret_cast<float4*>(&pp[ksl][1][4*h4]) = aS1;
        *reinterpret_cast<float4*>(&pp[ksl][2][4*h4]) = aS2;
        *reinterpret_cast<float4*>(&pp[ksl][3][4*h4]) = aS3;
        *reinterpret_cast<float4*>(&pp[ksl][4][4*h4]) = aS4;
        *reinterpret_cast<float4*>(&pp[ksl][5][4*h4]) = aS5;
        __syncthreads();
        for (int i = tid; i < 768; i += 512){
            int r = i >> 7, h = i & 127;
            float acc = 0.f;
            #pragma unroll
            for (int q = 0; q < 16; ++q) acc += pp[q][r][h];
            zsrc[(m0 + r) * HD + h] = acc;
        }
        __syncthreads();
        *reinterpret_cast<float4*>(&pp[ksl][0][4*h4]) = aD0;
        *reinterpret_cast<float4*>(&pp[ksl][1][4*h4]) = aD1;
        *reinterpret_cast<float4*>(&pp[ksl][2][4*h4]) = aD2;
        *reinterpret_cast<float4*>(&pp[ksl][3][4*h4]) = aD3;
        *reinterpret_cast<float4*>(&pp[ksl][4][4*h4]) = aD4;
        *reinterpret_cast<float4*>(&pp[ksl][5][4*h4]) = aD5;
        __syncthreads();
        for (int i = tid; i < 768; i += 512){
            int r = i >> 7, h = i & 127;
            float acc = 0.f;
            #pragma unroll
            for (int q = 0; q < 16; ++q) acc += pp[q][r][h];
            zdst[(m0 + r) * HD + h] = acc;
        }
    }
}

// ---------- final stop (t = TT-1) ----------
__global__ void kstop_ker(const float* __restrict__ hid, const unsigned long long* __restrict__ msbuf,
                          const float* __restrict__ Wt, const float* __restrict__ bt,
                          float* __restrict__ out)
{
    int tid = threadIdx.x;
    if (tid < 12){
        int row = blockIdx.x * 6 + (tid >> 1), cc = tid & 1;
        float a2 = bt[cc];
        const float* hrow = hid + row * HD;
        #pragma unroll 8
        for (int k = 0; k < HD; ++k) a2 += hrow[k] * Wt[k * 2 + cc];
        const unsigned long long* msp = msbuf + ((TT - 1) & 1) * HD;
        const float sc = 1.0f / (768.0f * 1048576.0f);
        #pragma unroll 8
        for (int k = 0; k < HD; ++k){
            float mk = (float)(long long)msp[k] * sc;
            a2 += mk * Wt[(HD + k) * 2 + cc];
        }
        out[196608 + row * 8 + TT * 2 + cc] = 1.f / (1.f + expf(-a2));
    }
}

extern "C" void kernel_launch(void* const* d_in, const int* in_sizes, int n_in,
                              void* d_out, int out_size, void* d_ws, size_t ws_size,
                              hipStream_t stream){
    const float* states = (const float*)d_in[0];
    const float* edges  = (const float*)d_in[1];
    const float* We = (const float*)d_in[2];
    const float* be = (const float*)d_in[3];
    const float* Wm = (const float*)d_in[4];
    const float* bm = (const float*)d_in[5];
    const float* Wu = (const float*)d_in[6];
    const float* bu = (const float*)d_in[7];
    const float* Wd = (const float*)d_in[8];
    const float* bd = (const float*)d_in[9];
    const float* Wt = (const float*)d_in[10];
    const float* bt = (const float*)d_in[11];
    float* out = (float*)d_out;

    float* ws = (float*)d_ws;
    float* z       = ws;                        // 98304
    float* zsrc    = ws + 98304;                // 98304
    float* zdst    = ws + 196608;               // 98304
    float* hid     = ws + 294912;               // 98304
    float* state   = ws + 393216;               // 49152
    unsigned long long* msbuf = (unsigned long long*)(ws + 442368); // 256 ull = 512 f
    unsigned* u_enc = (unsigned*)(ws + 442880); // 3*768*128 = 294912 u32
    unsigned short* ebf = (unsigned short*)(ws + 737792); // 9437184 bf16

    k1_ker<<<768, 256, 0, stream>>>(states, edges, We, be, Wm, out, z, zsrc, zdst, ebf, u_enc);
    for (int t = 0; t < TT; ++t){
        k2_ker<<<512, 256, 0, stream>>>(ebf, zsrc, Wm, u_enc, hid, msbuf, Wt, bt, out, t);
        k3_ker<<<128, 512, 0, stream>>>(z, zsrc, zdst, u_enc, bm, Wu, bu, Wd, bd,
                                        We, be, Wm, hid, state, msbuf, out, t);
    }
    kstop_ker<<<128, 256, 0, stream>>>(hid, msbuf, Wt, bt, out);
}